// Round 1
// baseline (308.602 us; speedup 1.0000x reference)
//
#include <hip/hip_runtime.h>
#include <math.h>

// Problem constants (fixed by the reference).
#define NITEMS 50000
#define BATCH  512
#define LLEN   50
#define KTOP   20
#define HDIM   32
#define DDIM   32
#define NCH    5
#define NSEG   33          // H+1 piecewise-linear segments
#define NSCAL  (2*NCH*KTOP)   // 200 scalars per item
#define NCELL  (NCH*KTOP)     // 100 (c,k) cells
#define SLOTS  13             // ceil(100/8) cells per thread-group

// ws float layout:
//   [0, 160)        thr[c][h]
//   [160, 160+10560) AB[c][s][d] interleaved (A,B) float pairs
#define WS_THR  0
#define WS_AB   (NCH*HDIM)

// ---------------------------------------------------------------------------
// Setup: build per-(channel, segment) affine coefficients of the scalar MLP.
// o_c(x) = relu(x*w1 + b1) @ W2[c] + b2[c]  is piecewise linear in x with
// breakpoints thr_h = -b1_h/w1_h.  Segment s = #{h : thr_h < x}.
// Active set in segment s:  w1>0 & rank(h)<s  |  w1<0 & rank(h)>=s  | w1==0 & b1>0
// (rank = order of thr_h with index tie-break; boundary assignment is
// irrelevant because the function is continuous.)
// ---------------------------------------------------------------------------
__global__ void cnn_setup(const float* __restrict__ W1, const float* __restrict__ b1,
                          const float* __restrict__ W2, const float* __restrict__ b2,
                          float* __restrict__ ws) {
    int c = blockIdx.x / NSEG;
    int s = blockIdx.x % NSEG;
    int d = threadIdx.x;              // 0..31
    float A = 0.f, Bv = 0.f;
    for (int h = 0; h < HDIM; ++h) {
        float w   = W1[c*HDIM + h];
        float bb  = b1[c*HDIM + h];
        float thr = (w != 0.f) ? (-bb / w) : INFINITY;
        int rank = 0;
        for (int h2 = 0; h2 < HDIM; ++h2) {
            float w2v  = W1[c*HDIM + h2];
            float bb2  = b1[c*HDIM + h2];
            float thr2 = (w2v != 0.f) ? (-bb2 / w2v) : INFINITY;
            rank += (thr2 < thr || (thr2 == thr && h2 < h)) ? 1 : 0;
        }
        bool active;
        if      (w > 0.f) active = (rank <  s);
        else if (w < 0.f) active = (rank >= s);
        else              active = (bb > 0.f);
        if (active) {
            float w2 = W2[(c*HDIM + h)*DDIM + d];
            A  = fmaf(w,  w2, A);
            Bv = fmaf(bb, w2, Bv);
        }
        if (s == 0 && d == 0) ws[WS_THR + c*HDIM + h] = thr;
    }
    Bv += b2[c*DDIM + d];
    float* AB = ws + WS_AB;
    AB[((c*NSEG + s)*DDIM + d)*2 + 0] = A;
    AB[((c*NSEG + s)*DDIM + d)*2 + 1] = Bv;
}

// ---------------------------------------------------------------------------
// Main: one block per batch row b. 256 threads = 8 groups x 32 d-lanes.
// Loop over the user's items (l < len) accumulating rep sums in registers;
// final iteration (l == len) computes the target-item rep, fuses the mean,
// elementwise product, Wout dot (shuffle reduce over 32 lanes) and sigmoid.
// ---------------------------------------------------------------------------
__global__ __launch_bounds__(256, 2) void cnn_main(
        const float* __restrict__ ctx,  const float* __restrict__ ws,
        const float* __restrict__ Wout, const float* __restrict__ bout,
        const int* __restrict__ item_idxs, const int* __restrict__ user_items,
        const int* __restrict__ user_lens, float* __restrict__ out) {
    __shared__ float2 sAB[NCH*NSEG*DDIM];   // 42240 B, (A,B) pairs
    __shared__ float2 sxo[NSCAL];           // per-scalar (x, AB row byte-offset)
    __shared__ float  sWout[DDIM];

    const int tid = threadIdx.x;

    // Stage the AB table into LDS (coalesced float2 loads).
    const float2* ABg = reinterpret_cast<const float2*>(ws + WS_AB);
    for (int i = tid; i < NCH*NSEG*DDIM; i += 256) sAB[i] = ABg[i];
    if (tid < DDIM) sWout[tid] = Wout[tid];

    // Per-thread channel + register-resident thresholds for segment search.
    const int myc = tid / 40;               // scalar t -> channel t/40
    float thrr[HDIM];
#pragma unroll
    for (int h = 0; h < HDIM; ++h)
        thrr[h] = (tid < NSCAL) ? ws[WS_THR + myc*HDIM + h] : 0.f;

    const int b   = blockIdx.x;
    const int len = user_lens[b];
    const float inv_len = 1.f / (float)len;
    const float bo = bout[0];

    const int group = tid >> 5;             // 0..7
    const int d     = tid & 31;

    int t0s[SLOTS];
#pragma unroll
    for (int i = 0; i < SLOTS; ++i) {
        int cell = group + 8*i;             // cell = c*20 + k
        t0s[i] = (cell / KTOP) * (2*KTOP) + (cell % KTOP);  // scalar idx of pair p=0
    }
    float acc[SLOTS];
#pragma unroll
    for (int i = 0; i < SLOTS; ++i) acc[i] = 0.f;

    __syncthreads();

    for (int l = 0; l <= len; ++l) {
        const int item = (l < len) ? user_items[b*LLEN + l] : item_idxs[b];

        // ---- phase S: per-scalar segment search -------------------------
        if (tid < NSCAL) {
            float x = ctx[(size_t)item * NSCAL + tid];
            int s = 0;
#pragma unroll
            for (int h = 0; h < HDIM; ++h) s += (thrr[h] < x) ? 1 : 0;
            int off = (myc*NSEG + s) << 8;  // byte offset of AB row (32 float2)
            sxo[tid] = make_float2(x, __int_as_float(off));
        }
        __syncthreads();

        // ---- phase C: per-(cell,d) affine eval + product ----------------
        if (l < len) {
#pragma unroll
            for (int i = 0; i < SLOTS; ++i) {
                int cell = group + 8*i;
                if (cell < NCELL) {
                    float2 xo0 = sxo[t0s[i]];
                    float2 xo1 = sxo[t0s[i] + KTOP];
                    const float2* p0 = (const float2*)((const char*)sAB + __float_as_int(xo0.y)) + d;
                    const float2* p1 = (const float2*)((const char*)sAB + __float_as_int(xo1.y)) + d;
                    float2 ab0 = *p0;
                    float2 ab1 = *p1;
                    float o0 = fmaf(xo0.x, ab0.x, ab0.y);
                    float o1 = fmaf(xo1.x, ab1.x, ab1.y);
                    acc[i] = fmaf(o0, o1, acc[i]);
                }
            }
        } else {
            // target item: fuse mean, product, Wout dot, sigmoid
#pragma unroll
            for (int i = 0; i < SLOTS; ++i) {
                int cell = group + 8*i;
                if (cell < NCELL) {
                    float2 xo0 = sxo[t0s[i]];
                    float2 xo1 = sxo[t0s[i] + KTOP];
                    const float2* p0 = (const float2*)((const char*)sAB + __float_as_int(xo0.y)) + d;
                    const float2* p1 = (const float2*)((const char*)sAB + __float_as_int(xo1.y)) + d;
                    float2 ab0 = *p0;
                    float2 ab1 = *p1;
                    float o0  = fmaf(xo0.x, ab0.x, ab0.y);
                    float o1  = fmaf(xo1.x, ab1.x, ab1.y);
                    float rep = o0 * o1;
                    float v = acc[i] * inv_len * rep * sWout[d];
                    // reduce over the 32 d-lanes (stays within half-wave)
#pragma unroll
                    for (int m = 16; m >= 1; m >>= 1) v += __shfl_xor(v, m, 64);
                    if (d == 0) out[b*NCELL + cell] = 1.f / (1.f + expf(-(v + bo)));
                }
            }
        }
        __syncthreads();
    }
}

extern "C" void kernel_launch(void* const* d_in, const int* in_sizes, int n_in,
                              void* d_out, int out_size, void* d_ws, size_t ws_size,
                              hipStream_t stream) {
    const float* ctx   = (const float*)d_in[0];
    const float* W1    = (const float*)d_in[1];
    const float* b1    = (const float*)d_in[2];
    const float* W2    = (const float*)d_in[3];
    const float* b2    = (const float*)d_in[4];
    const float* Wout  = (const float*)d_in[5];
    const float* bout  = (const float*)d_in[6];
    const int* item_idxs  = (const int*)d_in[7];
    const int* user_items = (const int*)d_in[8];
    const int* user_lens  = (const int*)d_in[9];
    float* out = (float*)d_out;
    float* ws  = (float*)d_ws;   // needs 10720 floats = 42,880 B

    cnn_setup<<<NCH*NSEG, 32, 0, stream>>>(W1, b1, W2, b2, ws);
    cnn_main<<<BATCH, 256, 0, stream>>>(ctx, ws, Wout, bout,
                                        item_idxs, user_items, user_lens, out);
}

// Round 2
// 166.976 us; speedup vs baseline: 1.8482x; 1.8482x over previous
//
#include <hip/hip_runtime.h>
#include <math.h>

// Problem constants (fixed by the reference).
#define NITEMS 50000
#define BATCH  512
#define LLEN   50
#define KTOP   20
#define HDIM   32
#define DDIM   32
#define NCH    5
#define NSEG   33             // H+1 piecewise-linear segments
#define NSCAL  (2*NCH*KTOP)   // 200 scalars per item
#define NCELL  (NCH*KTOP)     // 100 (c,k) cells
#define SLOTS  13             // ceil(100/8) cells per thread-group

// ws float layout:
//   [0, 160)         thr[c][h]
//   [160, 160+10560) AB[c][s][d] interleaved (A,B) float pairs
#define WS_THR  0
#define WS_AB   (NCH*HDIM)

// ---------------------------------------------------------------------------
// Setup: per-(channel, segment) affine coefficients of the scalar MLP.
// o_c(x) = relu(x*w1 + b1) @ W2[c] + b2[c]  is piecewise linear in x with
// breakpoints thr_h = -b1_h/w1_h; segment s = #{h : thr_h < x}.
// One block per segment s; weights staged in LDS (R1 post-mortem: the old
// 32-thread global-rank-loop version was 140 us latency-bound at 1.7% occ).
// ---------------------------------------------------------------------------
__global__ __launch_bounds__(256) void cnn_setup(
        const float* __restrict__ W1, const float* __restrict__ b1,
        const float* __restrict__ W2, const float* __restrict__ b2,
        float* __restrict__ ws) {
    __shared__ float sW1[NCH*HDIM], sB1[NCH*HDIM], sThr[NCH*HDIM];
    __shared__ int   sRank[NCH*HDIM];
    __shared__ float sW2[NCH*HDIM*DDIM];     // 20 KB
    __shared__ float sB2[NCH*DDIM];
    const int tid = threadIdx.x;

    for (int i = tid; i < NCH*HDIM; i += 256) { sW1[i] = W1[i]; sB1[i] = b1[i]; }
    for (int i = tid; i < NCH*HDIM*DDIM; i += 256) sW2[i] = W2[i];
    for (int i = tid; i < NCH*DDIM; i += 256) sB2[i] = b2[i];
    __syncthreads();

    for (int i = tid; i < NCH*HDIM; i += 256) {
        float w = sW1[i];
        sThr[i] = (w != 0.f) ? (-sB1[i] / w) : INFINITY;
    }
    __syncthreads();

    for (int i = tid; i < NCH*HDIM; i += 256) {
        int c = i / HDIM, h = i % HDIM;
        float thr = sThr[i];
        int rank = 0;
        for (int h2 = 0; h2 < HDIM; ++h2) {
            float thr2 = sThr[c*HDIM + h2];
            rank += (thr2 < thr || (thr2 == thr && h2 < h)) ? 1 : 0;
        }
        sRank[i] = rank;
        if (blockIdx.x == 0) ws[WS_THR + i] = thr;   // thresholds written once
    }
    __syncthreads();

    const int s = blockIdx.x;                 // segment
    if (tid < NCH*DDIM) {
        int c = tid / DDIM, d = tid % DDIM;
        float A = 0.f, Bv = 0.f;
#pragma unroll
        for (int h = 0; h < HDIM; ++h) {
            float w  = sW1[c*HDIM + h];
            float bb = sB1[c*HDIM + h];
            int   r  = sRank[c*HDIM + h];
            bool active = (w > 0.f) ? (r < s) : ((w < 0.f) ? (r >= s) : (bb > 0.f));
            if (active) {
                float w2 = sW2[(c*HDIM + h)*DDIM + d];
                A  = fmaf(w,  w2, A);
                Bv = fmaf(bb, w2, Bv);
            }
        }
        Bv += sB2[c*DDIM + d];
        float* AB = ws + WS_AB;
        AB[((c*NSEG + s)*DDIM + d)*2 + 0] = A;
        AB[((c*NSEG + s)*DDIM + d)*2 + 1] = Bv;
    }
}

// ---------------------------------------------------------------------------
// Main: one block per batch row b. 256 threads = 8 groups x 32 d-lanes.
// Ping-pong sxo buffer -> ONE barrier per item; next item's 200 ctx scalars
// are prefetched into registers before the barrier to hide gather latency.
// Final iteration (l == len) is the target item: fuses mean, product, Wout
// dot (half-wave shuffle reduce) and sigmoid.
// ---------------------------------------------------------------------------
__global__ __launch_bounds__(256, 3) void cnn_main(
        const float* __restrict__ ctx,  const float* __restrict__ ws,
        const float* __restrict__ Wout, const float* __restrict__ bout,
        const int* __restrict__ item_idxs, const int* __restrict__ user_items,
        const int* __restrict__ user_lens, float* __restrict__ out) {
    __shared__ float2 sAB[NCH*NSEG*DDIM];   // 42240 B, (A,B) pairs
    __shared__ float2 sxo[2][NSCAL];        // ping-pong (x, AB row byte-offset)
    __shared__ float  sWout[DDIM];

    const int tid = threadIdx.x;

    // Stage the AB table into LDS (coalesced float2 loads).
    const float2* ABg = reinterpret_cast<const float2*>(ws + WS_AB);
    for (int i = tid; i < NCH*NSEG*DDIM; i += 256) sAB[i] = ABg[i];
    if (tid < DDIM) sWout[tid] = Wout[tid];

    // Per-thread channel + register-resident thresholds for segment search.
    const int myc = tid / 40;               // scalar t -> channel t/40
    float thrr[HDIM];
#pragma unroll
    for (int h = 0; h < HDIM; ++h)
        thrr[h] = (tid < NSCAL) ? ws[WS_THR + myc*HDIM + h] : 0.f;

    const int b   = blockIdx.x;
    const int len = user_lens[b];           // guaranteed >= 1
    const float inv_len = 1.f / (float)len;
    const float bo = bout[0];

    const int group = tid >> 5;             // 0..7
    const int d     = tid & 31;

    int t0s[SLOTS];
#pragma unroll
    for (int i = 0; i < SLOTS; ++i) {
        int cell = group + 8*i;             // cell = c*20 + k
        t0s[i] = (cell / KTOP) * (2*KTOP) + (cell % KTOP);  // pair p=0 scalar idx
    }
    float acc[SLOTS];
#pragma unroll
    for (int i = 0; i < SLOTS; ++i) acc[i] = 0.f;

    // Preload item 0 (len >= 1 so item 0 is always a user item).
    float x = 0.f;
    {
        int item0 = user_items[b*LLEN + 0];
        if (tid < NSCAL) x = ctx[(size_t)item0 * NSCAL + tid];
    }

    __syncthreads();

    int p = 0;
    for (int l = 0; l <= len; ++l) {
        // ---- phase S: per-scalar segment search on register-held x ------
        if (tid < NSCAL) {
            int s = 0;
#pragma unroll
            for (int h = 0; h < HDIM; ++h) s += (thrr[h] < x) ? 1 : 0;
            int off = (myc*NSEG + s) << 8;  // byte offset of AB row (32 float2)
            sxo[p][tid] = make_float2(x, __int_as_float(off));
        }

        // ---- prefetch next item's scalars (hidden behind phase C) -------
        float xn = 0.f;
        if (l < len) {
            int nitem = (l + 1 < len) ? user_items[b*LLEN + l + 1] : item_idxs[b];
            if (tid < NSCAL) xn = ctx[(size_t)nitem * NSCAL + tid];
        }

        __syncthreads();   // orders S(l) writes before C(l) reads; S(l+1)
                           // writes buffer 1-p so it can't race C(l).

        // ---- phase C: per-(cell,d) affine eval + product ----------------
        if (l < len) {
#pragma unroll
            for (int i = 0; i < SLOTS; ++i) {
                int cell = group + 8*i;
                if (cell < NCELL) {
                    float2 xo0 = sxo[p][t0s[i]];
                    float2 xo1 = sxo[p][t0s[i] + KTOP];
                    const float2* p0 = (const float2*)((const char*)sAB + __float_as_int(xo0.y)) + d;
                    const float2* p1 = (const float2*)((const char*)sAB + __float_as_int(xo1.y)) + d;
                    float2 ab0 = *p0;
                    float2 ab1 = *p1;
                    float o0 = fmaf(xo0.x, ab0.x, ab0.y);
                    float o1 = fmaf(xo1.x, ab1.x, ab1.y);
                    acc[i] = fmaf(o0, o1, acc[i]);
                }
            }
        } else {
            // target item: fuse mean, product, Wout dot, sigmoid
#pragma unroll
            for (int i = 0; i < SLOTS; ++i) {
                int cell = group + 8*i;
                if (cell < NCELL) {
                    float2 xo0 = sxo[p][t0s[i]];
                    float2 xo1 = sxo[p][t0s[i] + KTOP];
                    const float2* p0 = (const float2*)((const char*)sAB + __float_as_int(xo0.y)) + d;
                    const float2* p1 = (const float2*)((const char*)sAB + __float_as_int(xo1.y)) + d;
                    float2 ab0 = *p0;
                    float2 ab1 = *p1;
                    float o0  = fmaf(xo0.x, ab0.x, ab0.y);
                    float o1  = fmaf(xo1.x, ab1.x, ab1.y);
                    float rep = o0 * o1;
                    float v = acc[i] * inv_len * rep * sWout[d];
#pragma unroll
                    for (int m = 16; m >= 1; m >>= 1) v += __shfl_xor(v, m, 64);
                    if (d == 0) out[b*NCELL + cell] = 1.f / (1.f + expf(-(v + bo)));
                }
            }
        }
        x = xn;
        p ^= 1;
    }
}

extern "C" void kernel_launch(void* const* d_in, const int* in_sizes, int n_in,
                              void* d_out, int out_size, void* d_ws, size_t ws_size,
                              hipStream_t stream) {
    const float* ctx   = (const float*)d_in[0];
    const float* W1    = (const float*)d_in[1];
    const float* b1    = (const float*)d_in[2];
    const float* W2    = (const float*)d_in[3];
    const float* b2    = (const float*)d_in[4];
    const float* Wout  = (const float*)d_in[5];
    const float* bout  = (const float*)d_in[6];
    const int* item_idxs  = (const int*)d_in[7];
    const int* user_items = (const int*)d_in[8];
    const int* user_lens  = (const int*)d_in[9];
    float* out = (float*)d_out;
    float* ws  = (float*)d_ws;   // needs 10720 floats = 42,880 B

    cnn_setup<<<NSEG, 256, 0, stream>>>(W1, b1, W2, b2, ws);
    cnn_main<<<BATCH, 256, 0, stream>>>(ctx, ws, Wout, bout,
                                        item_idxs, user_items, user_lens, out);
}

// Round 3
// 156.873 us; speedup vs baseline: 1.9672x; 1.0644x over previous
//
#include <hip/hip_runtime.h>
#include <math.h>

// Problem constants (fixed by the reference).
#define NITEMS 50000
#define BATCH  512
#define LLEN   50
#define KTOP   20
#define HDIM   32
#define DDIM   32
#define NCH    5
#define NSEG   33             // H+1 piecewise-linear segments
#define NSCAL  (2*NCH*KTOP)   // 200 scalars per item
#define NCELL  (NCH*KTOP)     // 100 (c,k) cells
#define NGRP   16             // thread groups (16 lanes each, 2 d's per lane)
#define SLOTS  7              // ceil(100/16) cells per group

// ws layout (floats):
//   [0, 160)         thr[c][h]
//   [160, 10720)     AB[c][s][d] interleaved (A,B) float pairs
//   [10720, 11232)   row order (ints) from the length sort
#define WS_THR   0
#define WS_AB    (NCH*HDIM)
#define WS_ORDER 10720

// ---------------------------------------------------------------------------
// Setup: per-(channel, segment) affine coefficients of the scalar MLP.
// o_c(x) = relu(x*w1 + b1) @ W2[c] + b2[c]  is piecewise linear in x with
// breakpoints thr_h = -b1_h/w1_h; segment s = #{h : thr_h < x}.
// ---------------------------------------------------------------------------
__global__ __launch_bounds__(256) void cnn_setup(
        const float* __restrict__ W1, const float* __restrict__ b1,
        const float* __restrict__ W2, const float* __restrict__ b2,
        float* __restrict__ ws) {
    __shared__ float sW1[NCH*HDIM], sB1[NCH*HDIM], sThr[NCH*HDIM];
    __shared__ int   sRank[NCH*HDIM];
    __shared__ float sW2[NCH*HDIM*DDIM];     // 20 KB
    __shared__ float sB2[NCH*DDIM];
    const int tid = threadIdx.x;

    for (int i = tid; i < NCH*HDIM; i += 256) { sW1[i] = W1[i]; sB1[i] = b1[i]; }
    for (int i = tid; i < NCH*HDIM*DDIM; i += 256) sW2[i] = W2[i];
    for (int i = tid; i < NCH*DDIM; i += 256) sB2[i] = b2[i];
    __syncthreads();

    for (int i = tid; i < NCH*HDIM; i += 256) {
        float w = sW1[i];
        sThr[i] = (w != 0.f) ? (-sB1[i] / w) : INFINITY;
    }
    __syncthreads();

    for (int i = tid; i < NCH*HDIM; i += 256) {
        int c = i / HDIM, h = i % HDIM;
        float thr = sThr[i];
        int rank = 0;
        for (int h2 = 0; h2 < HDIM; ++h2) {
            float thr2 = sThr[c*HDIM + h2];
            rank += (thr2 < thr || (thr2 == thr && h2 < h)) ? 1 : 0;
        }
        sRank[i] = rank;
        if (blockIdx.x == 0) ws[WS_THR + i] = thr;
    }
    __syncthreads();

    const int s = blockIdx.x;                 // segment
    if (tid < NCH*DDIM) {
        int c = tid / DDIM, d = tid % DDIM;
        float A = 0.f, Bv = 0.f;
#pragma unroll
        for (int h = 0; h < HDIM; ++h) {
            float w  = sW1[c*HDIM + h];
            float bb = sB1[c*HDIM + h];
            int   r  = sRank[c*HDIM + h];
            bool active = (w > 0.f) ? (r < s) : ((w < 0.f) ? (r >= s) : (bb > 0.f));
            if (active) {
                float w2 = sW2[(c*HDIM + h)*DDIM + d];
                A  = fmaf(w,  w2, A);
                Bv = fmaf(bb, w2, Bv);
            }
        }
        Bv += sB2[c*DDIM + d];
        float* AB = ws + WS_AB;
        AB[((c*NSEG + s)*DDIM + d)*2 + 0] = A;
        AB[((c*NSEG + s)*DDIM + d)*2 + 1] = Bv;
    }
}

// ---------------------------------------------------------------------------
// Length sort: one block, bitonic over the 512 (len, row) pairs. Perf-only:
// main pairs rank c with rank 511-c so (presumed round-robin) per-CU work is
// ~constant. Any order is still CORRECT.
// ---------------------------------------------------------------------------
__global__ __launch_bounds__(512) void cnn_sort(const int* __restrict__ user_lens,
                                                int* __restrict__ order) {
    __shared__ int k512[BATCH], v512[BATCH];
    const int t = threadIdx.x;
    k512[t] = user_lens[t];
    v512[t] = t;
    __syncthreads();
    for (int k = 2; k <= BATCH; k <<= 1) {
        for (int j = k >> 1; j > 0; j >>= 1) {
            int ixj = t ^ j;
            if (ixj > t) {
                bool up = ((t & k) == 0);
                int ka = k512[t], kb = k512[ixj];
                if ((ka > kb) == up) {
                    k512[t] = kb; k512[ixj] = ka;
                    int va = v512[t]; v512[t] = v512[ixj]; v512[ixj] = va;
                }
            }
            __syncthreads();
        }
    }
    order[t] = v512[t];
}

// ---------------------------------------------------------------------------
// Main: one block per batch row (via sorted pairing). 256 threads = 16 groups
// x 16 lanes; each lane covers 2 adjacent d's so table reads are b128.
// Ping-pong sxo (one barrier/item) + register prefetch of next item's ctx.
// Final iteration (l == len) is the target item: fuses mean, product, Wout
// dot (16-lane shuffle reduce) and sigmoid.
// ---------------------------------------------------------------------------
__global__ __launch_bounds__(256, 3) void cnn_main(
        const float* __restrict__ ctx,  const float* __restrict__ ws,
        const float* __restrict__ Wout, const float* __restrict__ bout,
        const int* __restrict__ item_idxs, const int* __restrict__ user_items,
        const int* __restrict__ user_lens, const int* __restrict__ order,
        float* __restrict__ out) {
    __shared__ float4 sAB4[NCH*NSEG*NGRP];  // 42240 B; row = 16 float4 = 256 B
    __shared__ float4 sxo4[2][NCELL];       // (x0, off0, x1, off1) per cell
    __shared__ float  sWout[DDIM];

    const int tid = threadIdx.x;

    // Stage the AB table (same memory layout as ws AB region, float4 view).
    const float4* ABg = reinterpret_cast<const float4*>(ws + WS_AB);
    for (int i = tid; i < NCH*NSEG*NGRP; i += 256) sAB4[i] = ABg[i];
    if (tid < DDIM) sWout[tid] = Wout[tid];

    // Per-thread channel + register-resident thresholds for segment search.
    const int myc = tid / 40;               // scalar t -> channel t/40
    float thrr[HDIM];
#pragma unroll
    for (int h = 0; h < HDIM; ++h)
        thrr[h] = (tid < NSCAL) ? ws[WS_THR + myc*HDIM + h] : 0.f;

    // Sorted pairing: blockIdx<256 -> rank b; else rank 767-b. Covers each
    // row exactly once; pairs long rows with short rows per (likely) CU.
    const int rank = (blockIdx.x < 256) ? blockIdx.x : (767 - blockIdx.x);
    const int b    = order[rank];

    const int len = user_lens[b];           // >= 1
    const float inv_len = 1.f / (float)len;
    const float bo = bout[0];

    const int group = tid >> 4;             // 0..15
    const int d16   = tid & 15;             // covers d = 2*d16, 2*d16+1

    int t0s[SLOTS];
#pragma unroll
    for (int i = 0; i < SLOTS; ++i) {
        int cell = group + NGRP*i;          // cell = c*20 + k
        t0s[i] = (cell / KTOP) * (2*KTOP) + (cell % KTOP);  // pair p=0 scalar
    }
    float acca[SLOTS], accb[SLOTS];
#pragma unroll
    for (int i = 0; i < SLOTS; ++i) { acca[i] = 0.f; accb[i] = 0.f; }

    // Preload item 0 (len >= 1 so item 0 is always a user item).
    float x = 0.f;
    {
        int item0 = user_items[b*LLEN + 0];
        if (tid < NSCAL) x = ctx[(size_t)item0 * NSCAL + tid];
    }

    __syncthreads();

    int p = 0;
    for (int l = 0; l <= len; ++l) {
        // ---- phase S: segment search on register-held x -----------------
        if (tid < NSCAL) {
            int s = 0;
#pragma unroll
            for (int h = 0; h < HDIM; ++h) s += (thrr[h] < x) ? 1 : 0;
            int off = (myc*NSEG + s) << 8;  // byte offset of 256 B AB row
            int r  = tid % 40;
            int cell = myc*KTOP + (r % KTOP);
            int pp   = r / KTOP;            // which half of the float4
            float2* dst = reinterpret_cast<float2*>(&sxo4[p][cell]) + pp;
            *dst = make_float2(x, __int_as_float(off));
        }

        // ---- prefetch next item's scalars (hidden behind phase C) -------
        float xn = 0.f;
        if (l < len) {
            int nitem = (l + 1 < len) ? user_items[b*LLEN + l + 1] : item_idxs[b];
            if (tid < NSCAL) xn = ctx[(size_t)nitem * NSCAL + tid];
        }

        __syncthreads();   // S(l) before C(l); S(l+1) targets buffer 1-p.

        if (l < len) {
            // ---- phase C: affine eval + pair product, 2 d's per lane ----
#pragma unroll
            for (int i = 0; i < SLOTS; ++i) {
                int cell = group + NGRP*i;
                if (cell < NCELL) {
                    float4 xo = sxo4[p][cell];
                    const float4* p0 = (const float4*)((const char*)sAB4 + __float_as_int(xo.y)) + d16;
                    const float4* p1 = (const float4*)((const char*)sAB4 + __float_as_int(xo.w)) + d16;
                    float4 ab0 = *p0;
                    float4 ab1 = *p1;
                    float o0a = fmaf(xo.x, ab0.x, ab0.y);
                    float o0b = fmaf(xo.x, ab0.z, ab0.w);
                    float o1a = fmaf(xo.z, ab1.x, ab1.y);
                    float o1b = fmaf(xo.z, ab1.z, ab1.w);
                    acca[i] = fmaf(o0a, o1a, acca[i]);
                    accb[i] = fmaf(o0b, o1b, accb[i]);
                }
            }
        } else {
            // target item: fuse mean, product, Wout dot, sigmoid
#pragma unroll
            for (int i = 0; i < SLOTS; ++i) {
                int cell = group + NGRP*i;
                if (cell < NCELL) {
                    float4 xo = sxo4[p][cell];
                    const float4* p0 = (const float4*)((const char*)sAB4 + __float_as_int(xo.y)) + d16;
                    const float4* p1 = (const float4*)((const char*)sAB4 + __float_as_int(xo.w)) + d16;
                    float4 ab0 = *p0;
                    float4 ab1 = *p1;
                    float repa = fmaf(xo.x, ab0.x, ab0.y) * fmaf(xo.z, ab1.x, ab1.y);
                    float repb = fmaf(xo.x, ab0.z, ab0.w) * fmaf(xo.z, ab1.z, ab1.w);
                    float v = (acca[i] * repa * sWout[2*d16] +
                               accb[i] * repb * sWout[2*d16 + 1]) * inv_len;
                    // reduce over the 16 lanes of this group
#pragma unroll
                    for (int m = 8; m >= 1; m >>= 1) v += __shfl_xor(v, m, 64);
                    if (d16 == 0) out[b*NCELL + cell] = 1.f / (1.f + expf(-(v + bo)));
                }
            }
        }
        x = xn;
        p ^= 1;
    }
}

extern "C" void kernel_launch(void* const* d_in, const int* in_sizes, int n_in,
                              void* d_out, int out_size, void* d_ws, size_t ws_size,
                              hipStream_t stream) {
    const float* ctx   = (const float*)d_in[0];
    const float* W1    = (const float*)d_in[1];
    const float* b1    = (const float*)d_in[2];
    const float* W2    = (const float*)d_in[3];
    const float* b2    = (const float*)d_in[4];
    const float* Wout  = (const float*)d_in[5];
    const float* bout  = (const float*)d_in[6];
    const int* item_idxs  = (const int*)d_in[7];
    const int* user_items = (const int*)d_in[8];
    const int* user_lens  = (const int*)d_in[9];
    float* out = (float*)d_out;
    float* ws  = (float*)d_ws;                 // uses 44,928 B
    int*   order = (int*)(ws + WS_ORDER);

    cnn_setup<<<NSEG, 256, 0, stream>>>(W1, b1, W2, b2, ws);
    cnn_sort<<<1, 512, 0, stream>>>(user_lens, order);
    cnn_main<<<BATCH, 256, 0, stream>>>(ctx, ws, Wout, bout,
                                        item_idxs, user_items, user_lens,
                                        order, out);
}

// Round 4
// 150.667 us; speedup vs baseline: 2.0482x; 1.0412x over previous
//
#include <hip/hip_runtime.h>
#include <math.h>

// Problem constants (fixed by the reference).
#define NITEMS 50000
#define BATCH  512
#define LLEN   50
#define KTOP   20
#define HDIM   32
#define DDIM   32
#define NCH    5
#define NSEG   33             // H+1 piecewise-linear segments
#define NSCAL  (2*NCH*KTOP)   // 200 scalars per item
#define NCELL  (NCH*KTOP)     // 100 (c,k) cells
#define NGRP   16             // thread groups (16 lanes each, 2 d's per lane)
#define SLOTS  7              // ceil(100/16) cells per group

// ws layout (floats):
//   [0, 160)         thr[c][h]
//   [160, 10720)     AB[c][s][d] interleaved (A,B) float pairs
//   [10720, 11232)   row order (ints) from the length sort
#define WS_THR   0
#define WS_AB    (NCH*HDIM)
#define WS_ORDER 10720

// ---------------------------------------------------------------------------
// Setup + sort, one dispatch (saves a graph node; R3 accounting showed ~5-8us
// per extra launch).  Blocks 0..32: per-(channel, segment) affine coeffs of
// the scalar MLP -- o_c(x) = relu(x*w1+b1)@W2[c]+b2[c] is piecewise linear
// with breakpoints thr_h = -b1_h/w1_h; segment s = #{h : thr_h < x}.
// Block 33: bitonic sort of the 512 lens (256 threads, 256 pairs/step);
// perf-only row permutation so main can pair long rows with short rows.
// ---------------------------------------------------------------------------
__global__ __launch_bounds__(256) void cnn_setup(
        const float* __restrict__ W1, const float* __restrict__ b1,
        const float* __restrict__ W2, const float* __restrict__ b2,
        const int* __restrict__ user_lens,
        float* __restrict__ ws, int* __restrict__ order) {
    const int tid = threadIdx.x;

    if (blockIdx.x < NSEG) {
        __shared__ float sW1[NCH*HDIM], sB1[NCH*HDIM], sThr[NCH*HDIM];
        __shared__ int   sRank[NCH*HDIM];
        __shared__ float sW2[NCH*HDIM*DDIM];     // 20 KB
        __shared__ float sB2[NCH*DDIM];

        for (int i = tid; i < NCH*HDIM; i += 256) { sW1[i] = W1[i]; sB1[i] = b1[i]; }
        for (int i = tid; i < NCH*HDIM*DDIM; i += 256) sW2[i] = W2[i];
        for (int i = tid; i < NCH*DDIM; i += 256) sB2[i] = b2[i];
        __syncthreads();

        for (int i = tid; i < NCH*HDIM; i += 256) {
            float w = sW1[i];
            sThr[i] = (w != 0.f) ? (-sB1[i] / w) : INFINITY;
        }
        __syncthreads();

        for (int i = tid; i < NCH*HDIM; i += 256) {
            int c = i / HDIM, h = i % HDIM;
            float thr = sThr[i];
            int rank = 0;
            for (int h2 = 0; h2 < HDIM; ++h2) {
                float thr2 = sThr[c*HDIM + h2];
                rank += (thr2 < thr || (thr2 == thr && h2 < h)) ? 1 : 0;
            }
            sRank[i] = rank;
            if (blockIdx.x == 0) ws[WS_THR + i] = thr;
        }
        __syncthreads();

        const int s = blockIdx.x;                 // segment
        if (tid < NCH*DDIM) {
            int c = tid / DDIM, d = tid % DDIM;
            float A = 0.f, Bv = 0.f;
#pragma unroll
            for (int h = 0; h < HDIM; ++h) {
                float w  = sW1[c*HDIM + h];
                float bb = sB1[c*HDIM + h];
                int   r  = sRank[c*HDIM + h];
                bool active = (w > 0.f) ? (r < s) : ((w < 0.f) ? (r >= s) : (bb > 0.f));
                if (active) {
                    float w2 = sW2[(c*HDIM + h)*DDIM + d];
                    A  = fmaf(w,  w2, A);
                    Bv = fmaf(bb, w2, Bv);
                }
            }
            Bv += sB2[c*DDIM + d];
            float* AB = ws + WS_AB;
            AB[((c*NSEG + s)*DDIM + d)*2 + 0] = A;
            AB[((c*NSEG + s)*DDIM + d)*2 + 1] = Bv;
        }
    } else {
        // ---- bitonic sort of (len, row), 256 threads over 512 elements ----
        __shared__ int k512[BATCH], v512[BATCH];
        for (int i = tid; i < BATCH; i += 256) { k512[i] = user_lens[i]; v512[i] = i; }
        __syncthreads();
        for (int k = 2; k <= BATCH; k <<= 1) {
            for (int j = k >> 1; j > 0; j >>= 1) {
                // thread t owns pair p=t: i = insert 0-bit at position log2(j)
                int i   = ((tid & ~(j - 1)) << 1) | (tid & (j - 1));
                int ixj = i | j;
                bool up = ((i & k) == 0);
                int ka = k512[i], kb = k512[ixj];
                if ((ka > kb) == up) {
                    k512[i] = kb; k512[ixj] = ka;
                    int va = v512[i]; v512[i] = v512[ixj]; v512[ixj] = va;
                }
                __syncthreads();
            }
        }
        for (int i = tid; i < BATCH; i += 256) order[i] = v512[i];
    }
}

// ---------------------------------------------------------------------------
// Main: one block per batch row (via sorted pairing). 256 threads = 16 groups
// x 16 lanes; each lane covers 2 adjacent d's so table reads are b128.
// Ping-pong sxo, ONE barrier per item. R4 fix: the next-item ctx prefetch is
// issued AFTER the barrier and consumed (phase S of l+1) BEFORE the next
// barrier, so the gather latency overlaps phase C instead of being drained
// by the barrier's implicit s_waitcnt vmcnt(0) (R3's mistake: issue before
// barrier exposed the full latency every iteration).
// ---------------------------------------------------------------------------
__global__ __launch_bounds__(256, 3) void cnn_main(
        const float* __restrict__ ctx,  const float* __restrict__ ws,
        const float* __restrict__ Wout, const float* __restrict__ bout,
        const int* __restrict__ item_idxs, const int* __restrict__ user_items,
        const int* __restrict__ user_lens, const int* __restrict__ order,
        float* __restrict__ out) {
    __shared__ float4 sAB4[NCH*NSEG*NGRP];  // 42240 B; row = 16 float4 = 256 B
    __shared__ float4 sxo4[2][NCELL];       // (x0, off0, x1, off1) per cell
    __shared__ float  sWout[DDIM];

    const int tid = threadIdx.x;

    // Stage the AB table (same memory layout as ws AB region, float4 view).
    const float4* ABg = reinterpret_cast<const float4*>(ws + WS_AB);
    for (int i = tid; i < NCH*NSEG*NGRP; i += 256) sAB4[i] = ABg[i];
    if (tid < DDIM) sWout[tid] = Wout[tid];

    // Per-thread channel + register-resident thresholds for segment search.
    const int myc = tid / 40;               // scalar t -> channel t/40
    float thrr[HDIM];
#pragma unroll
    for (int h = 0; h < HDIM; ++h)
        thrr[h] = (tid < NSCAL) ? ws[WS_THR + myc*HDIM + h] : 0.f;

    // Sorted pairing: blockIdx<256 -> rank b; else rank 767-b.  With 512
    // blocks round-robin over 256 CUs, co-residents are blocks b and b+256,
    // i.e. ranks r and 511-r -> per-CU item count ~ constant (~53).
    const int rank = (blockIdx.x < 256) ? blockIdx.x : (767 - blockIdx.x);
    const int b    = order[rank];

    const int len = user_lens[b];           // >= 1
    const float inv_len = 1.f / (float)len;
    const float bo = bout[0];

    const int group = tid >> 4;             // 0..15
    const int d16   = tid & 15;             // covers d = 2*d16, 2*d16+1

    float acca[SLOTS], accb[SLOTS];
#pragma unroll
    for (int i = 0; i < SLOTS; ++i) { acca[i] = 0.f; accb[i] = 0.f; }

    // Phase-S write slot for this thread (scalar index = tid when tid<200).
    const int s_r    = tid % 40;
    const int s_cell = myc*KTOP + (s_r % KTOP);
    const int s_pp   = s_r / KTOP;          // which float2 half of the float4

    // Preload item 0 (len >= 1 so item 0 is always a user item).
    float x = 0.f;
    {
        int item0 = user_items[b*LLEN + 0];
        if (tid < NSCAL) x = ctx[(size_t)item0 * NSCAL + tid];
    }

    __syncthreads();

    int p = 0;
    for (int l = 0; l <= len; ++l) {
        // ---- phase S: segment search on register-held x -----------------
        if (tid < NSCAL) {
            int s = 0;
#pragma unroll
            for (int h = 0; h < HDIM; ++h) s += (thrr[h] < x) ? 1 : 0;
            int off = (myc*NSEG + s) << 8;  // byte offset of 256 B AB row
            float2* dst = reinterpret_cast<float2*>(&sxo4[p][s_cell]) + s_pp;
            *dst = make_float2(x, __int_as_float(off));
        }

        __syncthreads();   // S(l) visible before C(l); S(l+1) targets 1-p.

        // ---- issue next item's gather NOW (after the barrier): its
        // latency overlaps phase C; it is consumed in S(l+1) before the
        // next barrier, so no barrier ever drains an unconsumed load.
        float xn = 0.f;
        if (l < len) {
            int nitem = (l + 1 < len) ? user_items[b*LLEN + l + 1] : item_idxs[b];
            if (tid < NSCAL) xn = ctx[(size_t)nitem * NSCAL + tid];
        }

        if (l < len) {
            // ---- phase C: affine eval + pair product, 2 d's per lane ----
#pragma unroll
            for (int i = 0; i < SLOTS; ++i) {
                int cell = group + NGRP*i;
                if (cell < NCELL) {
                    float4 xo = sxo4[p][cell];
                    const float4* p0 = (const float4*)((const char*)sAB4 + __float_as_int(xo.y)) + d16;
                    const float4* p1 = (const float4*)((const char*)sAB4 + __float_as_int(xo.w)) + d16;
                    float4 ab0 = *p0;
                    float4 ab1 = *p1;
                    float o0a = fmaf(xo.x, ab0.x, ab0.y);
                    float o0b = fmaf(xo.x, ab0.z, ab0.w);
                    float o1a = fmaf(xo.z, ab1.x, ab1.y);
                    float o1b = fmaf(xo.z, ab1.z, ab1.w);
                    acca[i] = fmaf(o0a, o1a, acca[i]);
                    accb[i] = fmaf(o0b, o1b, accb[i]);
                }
            }
        } else {
            // target item: fuse mean, product, Wout dot, sigmoid
#pragma unroll
            for (int i = 0; i < SLOTS; ++i) {
                int cell = group + NGRP*i;
                if (cell < NCELL) {
                    float4 xo = sxo4[p][cell];
                    const float4* p0 = (const float4*)((const char*)sAB4 + __float_as_int(xo.y)) + d16;
                    const float4* p1 = (const float4*)((const char*)sAB4 + __float_as_int(xo.w)) + d16;
                    float4 ab0 = *p0;
                    float4 ab1 = *p1;
                    float repa = fmaf(xo.x, ab0.x, ab0.y) * fmaf(xo.z, ab1.x, ab1.y);
                    float repb = fmaf(xo.x, ab0.z, ab0.w) * fmaf(xo.z, ab1.z, ab1.w);
                    float v = (acca[i] * repa * sWout[2*d16] +
                               accb[i] * repb * sWout[2*d16 + 1]) * inv_len;
                    // reduce over the 16 lanes of this group
#pragma unroll
                    for (int m = 8; m >= 1; m >>= 1) v += __shfl_xor(v, m, 64);
                    if (d16 == 0) out[b*NCELL + cell] = 1.f / (1.f + expf(-(v + bo)));
                }
            }
        }
        x = xn;
        p ^= 1;
    }
}

extern "C" void kernel_launch(void* const* d_in, const int* in_sizes, int n_in,
                              void* d_out, int out_size, void* d_ws, size_t ws_size,
                              hipStream_t stream) {
    const float* ctx   = (const float*)d_in[0];
    const float* W1    = (const float*)d_in[1];
    const float* b1    = (const float*)d_in[2];
    const float* W2    = (const float*)d_in[3];
    const float* b2    = (const float*)d_in[4];
    const float* Wout  = (const float*)d_in[5];
    const float* bout  = (const float*)d_in[6];
    const int* item_idxs  = (const int*)d_in[7];
    const int* user_items = (const int*)d_in[8];
    const int* user_lens  = (const int*)d_in[9];
    float* out = (float*)d_out;
    float* ws  = (float*)d_ws;                 // uses 44,928 B
    int*   order = (int*)(ws + WS_ORDER);

    cnn_setup<<<NSEG + 1, 256, 0, stream>>>(W1, b1, W2, b2, user_lens, ws, order);
    cnn_main<<<BATCH, 256, 0, stream>>>(ctx, ws, Wout, bout,
                                        item_idxs, user_items, user_lens,
                                        order, out);
}

// Round 5
// 134.240 us; speedup vs baseline: 2.2989x; 1.1224x over previous
//
#include <hip/hip_runtime.h>
#include <math.h>

// Problem constants (fixed by the reference).
#define NITEMS 50000
#define BATCH  512
#define LLEN   50
#define KTOP   20
#define HDIM   32
#define DDIM   32
#define NCH    5
#define NSEG   33             // H+1 piecewise-linear segments
#define NSCAL  200            // scalars per item
#define NCELL  100            // (c,k) cells
#define THRP   33             // padded LDS stride for sorted thresholds

// ws layout (floats):
//   [0, 160)         sorted thr[c][0..31] (ascending per channel)
//   [160, 10720)     AB[c][s][d] interleaved (A,B) float pairs
//   [10720, 11232)   row order (ints) from the length sort
#define WS_THRS  0
#define WS_AB    (NCH*HDIM)
#define WS_ORDER 10720

// ---------------------------------------------------------------------------
// Setup + sort, one dispatch. Blocks 0..32: per-(channel, segment) affine
// coeffs of the scalar MLP (piecewise-linear decomposition; segment
// s = #{h : thr_h < x}).  Block 0 additionally writes the per-channel SORTED
// thresholds (sRank is the sort permutation).  Block 33: bitonic sort of the
// 512 lens -> perf-only row permutation for load balancing.
// ---------------------------------------------------------------------------
__global__ __launch_bounds__(256) void cnn_setup(
        const float* __restrict__ W1, const float* __restrict__ b1,
        const float* __restrict__ W2, const float* __restrict__ b2,
        const int* __restrict__ user_lens,
        float* __restrict__ ws, int* __restrict__ order) {
    const int tid = threadIdx.x;

    if (blockIdx.x < NSEG) {
        __shared__ float sW1[NCH*HDIM], sB1[NCH*HDIM], sThr[NCH*HDIM];
        __shared__ int   sRank[NCH*HDIM];
        __shared__ float sW2[NCH*HDIM*DDIM];     // 20 KB
        __shared__ float sB2[NCH*DDIM];

        for (int i = tid; i < NCH*HDIM; i += 256) { sW1[i] = W1[i]; sB1[i] = b1[i]; }
        for (int i = tid; i < NCH*HDIM*DDIM; i += 256) sW2[i] = W2[i];
        for (int i = tid; i < NCH*DDIM; i += 256) sB2[i] = b2[i];
        __syncthreads();

        for (int i = tid; i < NCH*HDIM; i += 256) {
            float w = sW1[i];
            sThr[i] = (w != 0.f) ? (-sB1[i] / w) : INFINITY;
        }
        __syncthreads();

        for (int i = tid; i < NCH*HDIM; i += 256) {
            int c = i / HDIM, h = i % HDIM;
            float thr = sThr[i];
            int rank = 0;
            for (int h2 = 0; h2 < HDIM; ++h2) {
                float thr2 = sThr[c*HDIM + h2];
                rank += (thr2 < thr || (thr2 == thr && h2 < h)) ? 1 : 0;
            }
            sRank[i] = rank;
            // sorted thresholds: sorted[rank] = thr  (rank is a permutation)
            if (blockIdx.x == 0) ws[WS_THRS + c*HDIM + rank] = thr;
        }
        __syncthreads();

        const int s = blockIdx.x;                 // segment
        if (tid < NCH*DDIM) {
            int c = tid / DDIM, d = tid % DDIM;
            float A = 0.f, Bv = 0.f;
#pragma unroll
            for (int h = 0; h < HDIM; ++h) {
                float w  = sW1[c*HDIM + h];
                float bb = sB1[c*HDIM + h];
                int   r  = sRank[c*HDIM + h];
                bool active = (w > 0.f) ? (r < s) : ((w < 0.f) ? (r >= s) : (bb > 0.f));
                if (active) {
                    float w2 = sW2[(c*HDIM + h)*DDIM + d];
                    A  = fmaf(w,  w2, A);
                    Bv = fmaf(bb, w2, Bv);
                }
            }
            Bv += sB2[c*DDIM + d];
            float* AB = ws + WS_AB;
            AB[((c*NSEG + s)*DDIM + d)*2 + 0] = A;
            AB[((c*NSEG + s)*DDIM + d)*2 + 1] = Bv;
        }
    } else {
        // ---- bitonic sort of (len, row), 256 threads over 512 elements ----
        __shared__ int k512[BATCH], v512[BATCH];
        for (int i = tid; i < BATCH; i += 256) { k512[i] = user_lens[i]; v512[i] = i; }
        __syncthreads();
        for (int k = 2; k <= BATCH; k <<= 1) {
            for (int j = k >> 1; j > 0; j >>= 1) {
                int i   = ((tid & ~(j - 1)) << 1) | (tid & (j - 1));
                int ixj = i | j;
                bool up = ((i & k) == 0);
                int ka = k512[i], kb = k512[ixj];
                if ((ka > kb) == up) {
                    k512[i] = kb; k512[ixj] = ka;
                    int va = v512[i]; v512[i] = v512[ixj]; v512[ixj] = va;
                }
                __syncthreads();
            }
        }
        for (int i = tid; i < BATCH; i += 256) order[i] = v512[i];
    }
}

// ---------------------------------------------------------------------------
// Main (R5 rewrite): WAVE-AUTONOMOUS items.  One block per row; wave w
// handles items l = w, w+4, ... with NO per-item barrier (S->C exchange via
// per-wave LDS scratch; same-wave LDS ops are processed in order, and
// wave_barrier() pins compiler ordering).  Every wave first computes the
// TARGET item's rep folded with Wout into registers (wt); stripe items then
// accumulate a SCALAR per cell:  acc[cell] += sum_d rep_l[d] * wt[d].
// Output = sigmoid(sum_w acc / len + bout) -- exact since the combine is
// linear in the item-rep sum.  Barriers/block: 2 (staging + final reduce)
// instead of ~27 (R4 post-mortem: barrier lock-step, not gather latency,
// was the 55 us critical path).
// ---------------------------------------------------------------------------
__global__ __launch_bounds__(256, 2) void cnn_main(
        const float* __restrict__ ctx,  const float* __restrict__ ws,
        const float* __restrict__ Wout, const float* __restrict__ bout,
        const int* __restrict__ item_idxs, const int* __restrict__ user_items,
        const int* __restrict__ user_lens, const int* __restrict__ order,
        float* __restrict__ out) {
    __shared__ float4 sAB4[NCH*NSEG*16];    // 42240 B; (c,s) row = 16 float4
    __shared__ float  sThrS[NCH*THRP];      // sorted thr, stride 33 (bank-spread)
    __shared__ float4 sxo[4][NCELL];        // per-wave (x0,off0,x1,off1)
    __shared__ float  rawx[4][NSCAL];       // per-wave raw scalar staging
    __shared__ float  pRed[4][NCELL];       // per-wave scalar partials

    const int tid  = threadIdx.x;
    const int w    = tid >> 6;              // wave 0..3
    const int lane = tid & 63;
    const int g    = (lane >> 4) & 3;       // cell sub-group 0..3
    const int d16  = lane & 15;             // covers d = 2*d16, 2*d16+1

    // Stage table + sorted thresholds.
    const float4* ABg = reinterpret_cast<const float4*>(ws + WS_AB);
    for (int i = tid; i < NCH*NSEG*16; i += 256) sAB4[i] = ABg[i];
    for (int i = tid; i < NCH*THRP; i += 256) {
        int c = i / THRP, j = i - c*THRP;
        sThrS[i] = (j < HDIM) ? ws[WS_THRS + c*HDIM + j] : 0.f;
    }

    // Sorted pairing (ranks r and 511-r co-resident under round-robin).
    const int rank = (blockIdx.x < 256) ? blockIdx.x : (767 - blockIdx.x);
    const int b    = order[rank];
    const int len  = user_lens[b];          // >= 1
    const float inv_len = 1.f / (float)len;
    const float bo = bout[0];
    const float wa = Wout[2*d16], wb = Wout[2*d16 + 1];

    // Per-(lane,round) phase-S constants (fixed across items).
    int sc[4], sdst[4];
#pragma unroll
    for (int r = 0; r < 4; ++r) {
        int idx  = lane + 64*r;
        int c    = idx / 40, rr = idx - c*40;
        sc[r]    = c;
        sdst[r]  = (c*KTOP + (rr % KTOP))*2 + (rr / KTOP);  // float2 slot
    }

    const int nstripe = (len > w) ? ((len - w + 3) >> 2) : 0;
    const int nj = 1 + nstripe;             // j=0 is the target item

    float wta[25], wtb[25], acc[25];
#pragma unroll
    for (int i = 0; i < 25; ++i) acc[i] = 0.f;

    __syncthreads();                        // staging visible to all waves

    // Preload target row (j = 0).
    float4 x4 = make_float4(0.f, 0.f, 0.f, 0.f);
    {
        int it0 = item_idxs[b];
        if (lane < 50) x4 = *((const float4*)(ctx + (size_t)it0*NSCAL) + lane);
    }

    float2* sxoF2 = reinterpret_cast<float2*>(&sxo[w][0]);
    for (int j = 0; j < nj; ++j) {
        // stage this item's scalars into the per-wave scratch
        if (lane < 50) *((float4*)&rawx[w][0] + lane) = x4;
        __builtin_amdgcn_wave_barrier();

        // prefetch next item's row (latency hidden behind S+C, no barrier)
        float4 xn4 = make_float4(0.f, 0.f, 0.f, 0.f);
        if (j + 1 < nj) {
            int nit = user_items[b*LLEN + w + 4*j];
            if (lane < 50) xn4 = *((const float4*)(ctx + (size_t)nit*NSCAL) + lane);
        }

        // ---- phase S: binary-search segment for this wave's 200 scalars --
#pragma unroll
        for (int r = 0; r < 4; ++r) {
            int idx = lane + 64*r;
            if (idx < NSCAL) {
                float xv = rawx[w][idx];
                int base = sc[r]*THRP;
                int pos = 0;
                pos += (sThrS[base + pos + 15] < xv) ? 16 : 0;
                pos += (sThrS[base + pos + 7]  < xv) ? 8  : 0;
                pos += (sThrS[base + pos + 3]  < xv) ? 4  : 0;
                pos += (sThrS[base + pos + 1]  < xv) ? 2  : 0;
                pos += (sThrS[base + pos]      < xv) ? 1  : 0;
                int off = (sc[r]*NSEG + pos) << 8;   // byte offset of AB row
                sxoF2[sdst[r]] = make_float2(xv, __int_as_float(off));
            }
        }
        __builtin_amdgcn_wave_barrier();

        // ---- phase C: 100 cells x 32 d by this wave alone ----------------
        if (j == 0) {
            // target item: fold rep_t * Wout into registers
#pragma unroll
            for (int i = 0; i < 25; ++i) {
                float4 xo = sxo[w][i*4 + g];
                const float4* p0 = (const float4*)((const char*)sAB4 + __float_as_int(xo.y)) + d16;
                const float4* p1 = (const float4*)((const char*)sAB4 + __float_as_int(xo.w)) + d16;
                float4 ab0 = *p0, ab1 = *p1;
                wta[i] = fmaf(xo.x, ab0.x, ab0.y) * fmaf(xo.z, ab1.x, ab1.y) * wa;
                wtb[i] = fmaf(xo.x, ab0.z, ab0.w) * fmaf(xo.z, ab1.z, ab1.w) * wb;
            }
        } else {
#pragma unroll
            for (int i = 0; i < 25; ++i) {
                float4 xo = sxo[w][i*4 + g];
                const float4* p0 = (const float4*)((const char*)sAB4 + __float_as_int(xo.y)) + d16;
                const float4* p1 = (const float4*)((const char*)sAB4 + __float_as_int(xo.w)) + d16;
                float4 ab0 = *p0, ab1 = *p1;
                float ra = fmaf(xo.x, ab0.x, ab0.y) * fmaf(xo.z, ab1.x, ab1.y);
                float rb = fmaf(xo.x, ab0.z, ab0.w) * fmaf(xo.z, ab1.z, ab1.w);
                acc[i] = fmaf(ra, wta[i], fmaf(rb, wtb[i], acc[i]));
            }
        }
        __builtin_amdgcn_wave_barrier();
        x4 = xn4;
    }

    // ---- epilogue: 16-lane reduce, cross-wave combine, sigmoid ----------
#pragma unroll
    for (int i = 0; i < 25; ++i) {
        float v = acc[i];
        v += __shfl_xor(v, 1, 64);
        v += __shfl_xor(v, 2, 64);
        v += __shfl_xor(v, 4, 64);
        v += __shfl_xor(v, 8, 64);
        if (d16 == 0) pRed[w][i*4 + g] = v;
    }
    __syncthreads();
    if (tid < NCELL) {
        float p = pRed[0][tid] + pRed[1][tid] + pRed[2][tid] + pRed[3][tid];
        out[b*NCELL + tid] = 1.f / (1.f + expf(-(p*inv_len + bo)));
    }
}

extern "C" void kernel_launch(void* const* d_in, const int* in_sizes, int n_in,
                              void* d_out, int out_size, void* d_ws, size_t ws_size,
                              hipStream_t stream) {
    const float* ctx   = (const float*)d_in[0];
    const float* W1    = (const float*)d_in[1];
    const float* b1    = (const float*)d_in[2];
    const float* W2    = (const float*)d_in[3];
    const float* b2    = (const float*)d_in[4];
    const float* Wout  = (const float*)d_in[5];
    const float* bout  = (const float*)d_in[6];
    const int* item_idxs  = (const int*)d_in[7];
    const int* user_items = (const int*)d_in[8];
    const int* user_lens  = (const int*)d_in[9];
    float* out = (float*)d_out;
    float* ws  = (float*)d_ws;                 // uses 44,928 B
    int*   order = (int*)(ws + WS_ORDER);

    cnn_setup<<<NSEG + 1, 256, 0, stream>>>(W1, b1, W2, b2, user_lens, ws, order);
    cnn_main<<<BATCH, 256, 0, stream>>>(ctx, ws, Wout, bout,
                                        item_idxs, user_items, user_lens,
                                        order, out);
}

// Round 6
// 130.589 us; speedup vs baseline: 2.3631x; 1.0280x over previous
//
#include <hip/hip_runtime.h>
#include <math.h>

// Problem constants (fixed by the reference).
#define NITEMS 50000
#define BATCH  512
#define LLEN   50
#define KTOP   20
#define HDIM   32
#define DDIM   32
#define NCH    5
#define NSEG   33             // H+1 piecewise-linear segments
#define NSCAL  200            // scalars per item
#define NCELL  100            // (c,k) cells
#define THRP   33             // padded LDS stride for sorted thresholds
#define NWAVE  8              // waves per block (R6: was 4)

// ws layout (floats):
//   [0, 160)         sorted thr[c][0..31] (ascending per channel)
//   [160, 10720)     AB[c][s][d] interleaved (A,B) float pairs
//   [10720, 11232)   row order (ints) from the length sort
#define WS_THRS  0
#define WS_AB    (NCH*HDIM)
#define WS_ORDER 10720

// ---------------------------------------------------------------------------
// Setup + sort, one dispatch. Blocks 0..32: per-(channel, segment) affine
// coeffs of the scalar MLP (piecewise-linear decomposition; segment
// s = #{h : thr_h < x}).  Block 0 additionally writes the per-channel SORTED
// thresholds (sRank is the sort permutation).  Block 33: bitonic sort of the
// 512 lens -> perf-only row permutation for load balancing.
// ---------------------------------------------------------------------------
__global__ __launch_bounds__(256) void cnn_setup(
        const float* __restrict__ W1, const float* __restrict__ b1,
        const float* __restrict__ W2, const float* __restrict__ b2,
        const int* __restrict__ user_lens,
        float* __restrict__ ws, int* __restrict__ order) {
    const int tid = threadIdx.x;

    if (blockIdx.x < NSEG) {
        __shared__ float sW1[NCH*HDIM], sB1[NCH*HDIM], sThr[NCH*HDIM];
        __shared__ int   sRank[NCH*HDIM];
        __shared__ float sW2[NCH*HDIM*DDIM];     // 20 KB
        __shared__ float sB2[NCH*DDIM];

        for (int i = tid; i < NCH*HDIM; i += 256) { sW1[i] = W1[i]; sB1[i] = b1[i]; }
        for (int i = tid; i < NCH*HDIM*DDIM; i += 256) sW2[i] = W2[i];
        for (int i = tid; i < NCH*DDIM; i += 256) sB2[i] = b2[i];
        __syncthreads();

        for (int i = tid; i < NCH*HDIM; i += 256) {
            float w = sW1[i];
            sThr[i] = (w != 0.f) ? (-sB1[i] / w) : INFINITY;
        }
        __syncthreads();

        for (int i = tid; i < NCH*HDIM; i += 256) {
            int c = i / HDIM, h = i % HDIM;
            float thr = sThr[i];
            int rank = 0;
            for (int h2 = 0; h2 < HDIM; ++h2) {
                float thr2 = sThr[c*HDIM + h2];
                rank += (thr2 < thr || (thr2 == thr && h2 < h)) ? 1 : 0;
            }
            sRank[i] = rank;
            // sorted thresholds: sorted[rank] = thr  (rank is a permutation)
            if (blockIdx.x == 0) ws[WS_THRS + c*HDIM + rank] = thr;
        }
        __syncthreads();

        const int s = blockIdx.x;                 // segment
        if (tid < NCH*DDIM) {
            int c = tid / DDIM, d = tid % DDIM;
            float A = 0.f, Bv = 0.f;
#pragma unroll
            for (int h = 0; h < HDIM; ++h) {
                float w  = sW1[c*HDIM + h];
                float bb = sB1[c*HDIM + h];
                int   r  = sRank[c*HDIM + h];
                bool active = (w > 0.f) ? (r < s) : ((w < 0.f) ? (r >= s) : (bb > 0.f));
                if (active) {
                    float w2 = sW2[(c*HDIM + h)*DDIM + d];
                    A  = fmaf(w,  w2, A);
                    Bv = fmaf(bb, w2, Bv);
                }
            }
            Bv += sB2[c*DDIM + d];
            float* AB = ws + WS_AB;
            AB[((c*NSEG + s)*DDIM + d)*2 + 0] = A;
            AB[((c*NSEG + s)*DDIM + d)*2 + 1] = Bv;
        }
    } else {
        // ---- bitonic sort of (len, row), 256 threads over 512 elements ----
        __shared__ int k512[BATCH], v512[BATCH];
        for (int i = tid; i < BATCH; i += 256) { k512[i] = user_lens[i]; v512[i] = i; }
        __syncthreads();
        for (int k = 2; k <= BATCH; k <<= 1) {
            for (int j = k >> 1; j > 0; j >>= 1) {
                int i   = ((tid & ~(j - 1)) << 1) | (tid & (j - 1));
                int ixj = i | j;
                bool up = ((i & k) == 0);
                int ka = k512[i], kb = k512[ixj];
                if ((ka > kb) == up) {
                    k512[i] = kb; k512[ixj] = ka;
                    int va = v512[i]; v512[i] = v512[ixj]; v512[ixj] = va;
                }
                __syncthreads();
            }
        }
        for (int i = tid; i < BATCH; i += 256) order[i] = v512[i];
    }
}

// ---------------------------------------------------------------------------
// Main (R6): wave-autonomous items, 8 WAVES per block (512 threads), one
// batch row per block.  Wave w handles stripe items w, w+8, ... with no
// per-item barrier (per-wave LDS scratch; same-wave LDS ops are in-order,
// wave_barrier() pins compiler ordering).  Every wave first computes the
// TARGET item's rep folded with Wout into registers (wt); stripe items
// accumulate a SCALAR per cell (combine is linear in the item-rep sum).
// R5 post-mortem: critical path = longest wave's serial item-units
// (was 14 units, 8 waves/CU hiding).  R6: 8 units max, 16 waves/CU.
// LDS: per-wave scratch unioned with epilogue partials -> 62.1 KB,
// 2 blocks/CU.
// ---------------------------------------------------------------------------
__global__ __launch_bounds__(512, 4) void cnn_main(
        const float* __restrict__ ctx,  const float* __restrict__ ws,
        const float* __restrict__ Wout, const float* __restrict__ bout,
        const int* __restrict__ item_idxs, const int* __restrict__ user_items,
        const int* __restrict__ user_lens, const int* __restrict__ order,
        float* __restrict__ out) {
    __shared__ float4 sAB4[NCH*NSEG*16];    // 42240 B; (c,s) row = 16 float4
    __shared__ float  sThrS[NCH*THRP];      // sorted thr, stride 33
    __shared__ float4 sxo[NWAVE][NCELL];    // per-wave (x0,off0,x1,off1)
    __shared__ union WScr {                 // per-wave: loop scratch / partials
        float rawx[NSCAL];                  // raw scalars (loop phase)
        float pRed[NCELL];                  // scalar partials (epilogue only;
    } wscr[NWAVE];                          //  own-wave reuse -> race-free)

    const int tid  = threadIdx.x;
    const int w    = tid >> 6;              // wave 0..7
    const int lane = tid & 63;
    const int g    = (lane >> 4) & 3;       // cell sub-group 0..3
    const int d16  = lane & 15;             // covers d = 2*d16, 2*d16+1

    // Stage table + sorted thresholds.
    const float4* ABg = reinterpret_cast<const float4*>(ws + WS_AB);
    for (int i = tid; i < NCH*NSEG*16; i += 512) sAB4[i] = ABg[i];
    for (int i = tid; i < NCH*THRP; i += 512) {
        int c = i / THRP, j = i - c*THRP;
        sThrS[i] = (j < HDIM) ? ws[WS_THRS + c*HDIM + j] : 0.f;
    }

    // Sorted pairing (ranks r and 511-r co-resident under round-robin).
    const int rank = (blockIdx.x < 256) ? blockIdx.x : (767 - blockIdx.x);
    const int b    = order[rank];
    const int len  = user_lens[b];          // >= 1
    const float inv_len = 1.f / (float)len;
    const float bo = bout[0];
    const float wa = Wout[2*d16], wb = Wout[2*d16 + 1];

    // Per-(lane,round) phase-S constants (fixed across items).
    int sc[4], sdst[4];
#pragma unroll
    for (int r = 0; r < 4; ++r) {
        int idx  = lane + 64*r;
        int c    = idx / 40, rr = idx - c*40;
        sc[r]    = c;
        sdst[r]  = (c*KTOP + (rr % KTOP))*2 + (rr / KTOP);  // float2 slot
    }

    const int nstripe = (len > w) ? ((len - w + NWAVE - 1) / NWAVE) : 0;
    const int nj = 1 + nstripe;             // j=0 is the target item

    float wta[25], wtb[25], acc[25];
#pragma unroll
    for (int i = 0; i < 25; ++i) acc[i] = 0.f;

    __syncthreads();                        // staging visible to all waves

    // Preload target row (j = 0).
    float4 x4 = make_float4(0.f, 0.f, 0.f, 0.f);
    {
        int it0 = item_idxs[b];
        if (lane < 50) x4 = *((const float4*)(ctx + (size_t)it0*NSCAL) + lane);
    }

    float2* sxoF2 = reinterpret_cast<float2*>(&sxo[w][0]);
    for (int j = 0; j < nj; ++j) {
        // stage this item's scalars into the per-wave scratch
        if (lane < 50) *((float4*)&wscr[w].rawx[0] + lane) = x4;
        __builtin_amdgcn_wave_barrier();

        // prefetch next item's row (latency hidden behind S+C, no barrier)
        float4 xn4 = make_float4(0.f, 0.f, 0.f, 0.f);
        if (j + 1 < nj) {
            int nit = user_items[b*LLEN + w + NWAVE*j];
            if (lane < 50) xn4 = *((const float4*)(ctx + (size_t)nit*NSCAL) + lane);
        }

        // ---- phase S: binary-search segment for this wave's 200 scalars --
#pragma unroll
        for (int r = 0; r < 4; ++r) {
            int idx = lane + 64*r;
            if (idx < NSCAL) {
                float xv = wscr[w].rawx[idx];
                int base = sc[r]*THRP;
                int pos = 0;
                pos += (sThrS[base + pos + 15] < xv) ? 16 : 0;
                pos += (sThrS[base + pos + 7]  < xv) ? 8  : 0;
                pos += (sThrS[base + pos + 3]  < xv) ? 4  : 0;
                pos += (sThrS[base + pos + 1]  < xv) ? 2  : 0;
                pos += (sThrS[base + pos]      < xv) ? 1  : 0;
                int off = (sc[r]*NSEG + pos) << 8;   // byte offset of AB row
                sxoF2[sdst[r]] = make_float2(xv, __int_as_float(off));
            }
        }
        __builtin_amdgcn_wave_barrier();

        // ---- phase C: 100 cells x 32 d by this wave alone ----------------
        if (j == 0) {
            // target item: fold rep_t * Wout into registers
#pragma unroll
            for (int i = 0; i < 25; ++i) {
                float4 xo = sxo[w][i*4 + g];
                const float4* p0 = (const float4*)((const char*)sAB4 + __float_as_int(xo.y)) + d16;
                const float4* p1 = (const float4*)((const char*)sAB4 + __float_as_int(xo.w)) + d16;
                float4 ab0 = *p0, ab1 = *p1;
                wta[i] = fmaf(xo.x, ab0.x, ab0.y) * fmaf(xo.z, ab1.x, ab1.y) * wa;
                wtb[i] = fmaf(xo.x, ab0.z, ab0.w) * fmaf(xo.z, ab1.z, ab1.w) * wb;
            }
        } else {
#pragma unroll
            for (int i = 0; i < 25; ++i) {
                float4 xo = sxo[w][i*4 + g];
                const float4* p0 = (const float4*)((const char*)sAB4 + __float_as_int(xo.y)) + d16;
                const float4* p1 = (const float4*)((const char*)sAB4 + __float_as_int(xo.w)) + d16;
                float4 ab0 = *p0, ab1 = *p1;
                float ra = fmaf(xo.x, ab0.x, ab0.y) * fmaf(xo.z, ab1.x, ab1.y);
                float rb = fmaf(xo.x, ab0.z, ab0.w) * fmaf(xo.z, ab1.z, ab1.w);
                acc[i] = fmaf(ra, wta[i], fmaf(rb, wtb[i], acc[i]));
            }
        }
        __builtin_amdgcn_wave_barrier();
        x4 = xn4;
    }

    // ---- epilogue: 16-lane reduce, cross-wave combine, sigmoid ----------
#pragma unroll
    for (int i = 0; i < 25; ++i) {
        float v = acc[i];
        v += __shfl_xor(v, 1, 64);
        v += __shfl_xor(v, 2, 64);
        v += __shfl_xor(v, 4, 64);
        v += __shfl_xor(v, 8, 64);
        if (d16 == 0) wscr[w].pRed[i*4 + g] = v;   // own-wave slot: loop done
    }
    __syncthreads();
    if (tid < NCELL) {
        float p = 0.f;
#pragma unroll
        for (int q = 0; q < NWAVE; ++q) p += wscr[q].pRed[tid];
        out[b*NCELL + tid] = 1.f / (1.f + expf(-(p*inv_len + bo)));
    }
}

extern "C" void kernel_launch(void* const* d_in, const int* in_sizes, int n_in,
                              void* d_out, int out_size, void* d_ws, size_t ws_size,
                              hipStream_t stream) {
    const float* ctx   = (const float*)d_in[0];
    const float* W1    = (const float*)d_in[1];
    const float* b1    = (const float*)d_in[2];
    const float* W2    = (const float*)d_in[3];
    const float* b2    = (const float*)d_in[4];
    const float* Wout  = (const float*)d_in[5];
    const float* bout  = (const float*)d_in[6];
    const int* item_idxs  = (const int*)d_in[7];
    const int* user_items = (const int*)d_in[8];
    const int* user_lens  = (const int*)d_in[9];
    float* out = (float*)d_out;
    float* ws  = (float*)d_ws;                 // uses 44,928 B
    int*   order = (int*)(ws + WS_ORDER);

    cnn_setup<<<NSEG + 1, 256, 0, stream>>>(W1, b1, W2, b2, user_lens, ws, order);
    cnn_main<<<BATCH, 512, 0, stream>>>(ctx, ws, Wout, bout,
                                        item_idxs, user_items, user_lens,
                                        order, out);
}